// Round 5
// baseline (12937.027 us; speedup 1.0000x reference)
//
#include <hip/hip_runtime.h>
#include <math.h>

// ---------------------------------------------------------------------------
// Persistent 2-layer LSTM via MFMA split-bf16 (hi+lo, 3-term) fp32 emulation.
// 208 blocks x 512 thr (1/CU). Pipeline: A(64)=layer0 s=t | B(128)=layer1
// s=t-1 | C(16)=proj s=t-2. R4 flag barrier.
// R11: FULL-k LDS staging. h (hi+lo, 132 KB) fully resident per operand ->
// one staged fill per operand per step (A/C: 1 stall; B: h0 stalled once,
// h1 register-prefetched under the Wx1 phase via counted vmcnt(16) and
// raw lgkm barriers so the prefetch survives). Weight loads stay compiler-
// scheduled (R6 style, preserves nt-pair L2 reuse; R7/R9 asm prefetch broke
// it). B barriers/step: 16 (R6) -> 5.
// ---------------------------------------------------------------------------

typedef __attribute__((ext_vector_type(8))) short short8;
typedef __attribute__((ext_vector_type(4))) float f32x4;

constexpr int kV = 256, kH = 1024, kB = 32, kS = 512, G4H = 4096;
constexpr int NT = 512, NBLK = 208;
constexpr int NA = 64, B0 = 64, C0 = 192, ROOT = NBLK - 1;

// ws layout in SHORT units
constexpr long SZW = 4194304L;            // shorts per packed 1024x4096 matrix
constexpr long SZY = 262144L;             // shorts per packed Why array
constexpr long WP0H = 0,        WP0L = SZW;
constexpr long WP1XH = 2*SZW,   WP1XL = 3*SZW;
constexpr long WP1HH = 4*SZW,   WP1HL = 5*SZW;
constexpr long WYH  = 6*SZW,    WYL  = 6*SZW + SZY;
constexpr long HOFF = 6*SZW + 2*SZY;      // h arrays: h0h[2][32K],h0l,h1h,h1l

constexpr int HROW = 129;                 // short8 row stride (128 + 1 pad)

#define MFMA(a,b,c) __builtin_amdgcn_mfma_f32_16x16x32_bf16(a, b, c, 0, 0, 0)

// counted vmcnt wait + scheduler fence (keeps dependent LDS writes after it)
#define VM_WAIT(n) do { \
    asm volatile("s_waitcnt vmcnt(" #n ")" ::: "memory"); \
    __builtin_amdgcn_sched_barrier(0); \
  } while (0)

__device__ __forceinline__ float sigmoidf_(float v) { return 1.f / (1.f + expf(-v)); }

__device__ __forceinline__ void bf16split(float w, unsigned& hi, unsigned& lo) {
  unsigned u = __float_as_uint(w);
  unsigned r = (u + 0x7fffu + ((u >> 16) & 1u)) >> 16;
  float res = w - __uint_as_float(r << 16);
  unsigned u2 = __float_as_uint(res);
  unsigned r2 = (u2 + 0x7fffu + ((u2 >> 16) & 1u)) >> 16;
  hi = r; lo = r2;
}

// ---------------- coherent (cache-bypass) helpers --------------------------

__device__ __forceinline__ void coh_store_u32(unsigned* p, unsigned v) {
  asm volatile("global_store_dword %0, %1, off sc0 sc1" :: "v"(p), "v"(v) : "memory");
}
__device__ __forceinline__ void coh_store_u16(unsigned short* p, unsigned v) {
  asm volatile("global_store_short %0, %1, off sc0 sc1" :: "v"(p), "v"(v) : "memory");
}
__device__ __forceinline__ unsigned coh_load_u32(const unsigned* p) {
  unsigned v;
  asm volatile("global_load_dword %0, %1, off sc0 sc1\n\ts_waitcnt vmcnt(0)"
               : "=v"(v) : "v"(p) : "memory");
  return v;
}

// 8 coherent 16B loads at 256B stride, NO wait (p in shorts, +128/step)
__device__ __forceinline__ void ld8_coh(const unsigned short* p,
                                        float4& v0, float4& v1, float4& v2, float4& v3,
                                        float4& v4, float4& v5, float4& v6, float4& v7) {
  asm volatile(
      "global_load_dwordx4 %0, %8, off sc0 sc1\n\t"
      "global_load_dwordx4 %1, %9, off sc0 sc1\n\t"
      "global_load_dwordx4 %2, %10, off sc0 sc1\n\t"
      "global_load_dwordx4 %3, %11, off sc0 sc1\n\t"
      "global_load_dwordx4 %4, %12, off sc0 sc1\n\t"
      "global_load_dwordx4 %5, %13, off sc0 sc1\n\t"
      "global_load_dwordx4 %6, %14, off sc0 sc1\n\t"
      "global_load_dwordx4 %7, %15, off sc0 sc1"
      : "=&v"(v0), "=&v"(v1), "=&v"(v2), "=&v"(v3),
        "=&v"(v4), "=&v"(v5), "=&v"(v6), "=&v"(v7)
      : "v"(p), "v"(p + 128), "v"(p + 256), "v"(p + 384),
        "v"(p + 512), "v"(p + 640), "v"(p + 768), "v"(p + 896)
      : "memory");
}

// write one operand half (8 chunks) into the full-k LDS buffer
#define HWRITE8(H, bb, kg, a0,a1,a2,a3,a4,a5,a6,a7) do {            \
    (H)[(bb) * HROW + (kg) +   0] = __builtin_bit_cast(short8, a0); \
    (H)[(bb) * HROW + (kg) +  16] = __builtin_bit_cast(short8, a1); \
    (H)[(bb) * HROW + (kg) +  32] = __builtin_bit_cast(short8, a2); \
    (H)[(bb) * HROW + (kg) +  48] = __builtin_bit_cast(short8, a3); \
    (H)[(bb) * HROW + (kg) +  64] = __builtin_bit_cast(short8, a4); \
    (H)[(bb) * HROW + (kg) +  80] = __builtin_bit_cast(short8, a5); \
    (H)[(bb) * HROW + (kg) +  96] = __builtin_bit_cast(short8, a6); \
    (H)[(bb) * HROW + (kg) + 112] = __builtin_bit_cast(short8, a7); \
  } while (0)

// barrier that does NOT drain vmcnt: LDS-drain + raw s_barrier.
__device__ __forceinline__ void lds_barrier() {
  asm volatile("s_waitcnt lgkmcnt(0)" ::: "memory");
  __builtin_amdgcn_sched_barrier(0);
  __builtin_amdgcn_s_barrier();
  __builtin_amdgcn_sched_barrier(0);
}

// -------------------------- prep kernels -----------------------------------

__global__ void pack_w(const float* __restrict__ in, unsigned short* __restrict__ hi,
                       unsigned short* __restrict__ lo, int ncols) {
  int id = blockIdx.x * 256 + threadIdx.x;
  int slab = id / ncols, row = id % ncols;   // slab < 128
  int k0 = (slab >> 2) * 32 + (slab & 3) * 8;
  long ob = ((long)slab * ncols + row) * 8;
  #pragma unroll
  for (int e = 0; e < 8; ++e) {
    float w = in[(long)(k0 + e) * ncols + row];
    unsigned h_, l_;
    bf16split(w, h_, l_);
    hi[ob + e] = (unsigned short)h_;
    lo[ob + e] = (unsigned short)l_;
  }
}

__global__ void zero_state(unsigned* __restrict__ p, int n) {
  int i = blockIdx.x * 256 + threadIdx.x;
  if (i < n) p[i] = 0u;
}

// -------------------------- main persistent kernel -------------------------

extern "C" __global__ void __launch_bounds__(512, 1)
lstm_persist(const int* __restrict__ x,
             const float* __restrict__ Wx0,
             const float* __restrict__ b0v,
             const float* __restrict__ b1v,
             const float* __restrict__ byv,
             unsigned short* __restrict__ wss,
             float* __restrict__ out) {
  const short8* wp0h  = (const short8*)(wss + WP0H);
  const short8* wp0l  = (const short8*)(wss + WP0L);
  const short8* wp1xh = (const short8*)(wss + WP1XH);
  const short8* wp1xl = (const short8*)(wss + WP1XL);
  const short8* wp1hh = (const short8*)(wss + WP1HH);
  const short8* wp1hl = (const short8*)(wss + WP1HL);
  const short8* wyh   = (const short8*)(wss + WYH);
  const short8* wyl   = (const short8*)(wss + WYL);
  unsigned short* h0h = wss + HOFF;            // [2][32][1024]
  unsigned short* h0l = h0h + 65536;
  unsigned short* h1h = h0h + 131072;
  unsigned short* h1l = h0h + 196608;
  unsigned* arrive = (unsigned*)(h0h + 262144);  // stride-16 flags
  unsigned* gen = arrive + 4096;

  const int tid = threadIdx.x, blk = blockIdx.x;
  const int lane = tid & 63, m = lane & 15, quad = lane >> 4, w = tid >> 6;
  const int bb = tid >> 4, kg = tid & 15;      // staging row / chunk

  __shared__ short8 HSH[32 * HROW];   // 66 KB  h hi, full 1024-k
  __shared__ short8 HSL[32 * HROW];   // 66 KB  h lo, full 1024-k
  __shared__ float gx[2048];          // 8 KB gate/output exchange

  float c0r = 0.f, c1r = 0.f;

  // ---- loop-invariant bias loads (hoisted out of the t-loop) --------------
  float bA0 = 0.f, bA1 = 0.f, bA2 = 0.f, bA3 = 0.f;
  float bB0 = 0.f, bB1 = 0.f, bB2 = 0.f, bB3 = 0.f;
  float byr = 0.f;
  if (blk < NA) {
    const int u = tid >> 5, j2e = blk * 16 + u;
    bA0 = b0v[j2e];            bA1 = b0v[kH + j2e];
    bA2 = b0v[2 * kH + j2e];   bA3 = b0v[3 * kH + j2e];
  } else if (blk < C0) {
    if (tid < 256) {
      const int u = tid >> 5, j2e = (blk - B0) * 8 + u;
      bB0 = b1v[j2e];          bB1 = b1v[kH + j2e];
      bB2 = b1v[2 * kH + j2e]; bB3 = b1v[3 * kH + j2e];
    }
  } else {
    byr = byv[(blk - C0) * 16 + (tid & 15)];
  }

  #pragma unroll 1
  for (int t = 0; t < kS + 2; ++t) {
    if (blk < NA) {
      // ---------------- A: layer0 cell, s = t ---------------------------
      const int s = t;
      if (s < kS) {
        const int g = w >> 1, nt = w & 1, j0A = blk * 16;
        const int bcol = nt * 16 + m;
        const short8* aph = wp0h + quad * 4096 + (g * 1024 + j0A + m);
        const short8* apl = wp0l + quad * 4096 + (g * 1024 + j0A + m);
        const int rpar = (s + 1) & 1;
        const unsigned short* p0h = h0h + rpar * 32768 + bb * 1024 + kg * 8;
        const unsigned short* p0l = h0l + rpar * 32768 + bb * 1024 + kg * 8;
        const int ue = tid >> 5, be = tid & 31, j2e = j0A + ue;
        const int xs = x[be * kS + s];           // early (retired by VM_WAIT)
        float4 t0,t1,t2,t3,t4,t5,t6,t7, u0,u1,u2,u3,u4,u5,u6,u7;
        ld8_coh(p0h, t0,t1,t2,t3,t4,t5,t6,t7);
        ld8_coh(p0l, u0,u1,u2,u3,u4,u5,u6,u7);
        VM_WAIT(0);
        HWRITE8(HSH, bb, kg, t0,t1,t2,t3,t4,t5,t6,t7);
        HWRITE8(HSL, bb, kg, u0,u1,u2,u3,u4,u5,u6,u7);
        __syncthreads();
        // epilogue gather issued now; compiler sinks its wait to the epilogue
        const float* wxp = Wx0 + (long)xs * G4H + j2e;
        const float wxi = wxp[0], wxf = wxp[kH];
        const float wxg = wxp[2 * kH], wxo = wxp[3 * kH];
        f32x4 acc = {0.f, 0.f, 0.f, 0.f};
        #pragma unroll 1
        for (int hh = 0; hh < 2; ++hh) {
          #pragma unroll
          for (int kl = 0; kl < 16; ++kl) {
            const int kk = hh * 16 + kl;
            short8 ah = aph[kk * 16384];
            short8 al = apl[kk * 16384];
            short8 bh = HSH[bcol * HROW + kk * 4 + quad];
            short8 bl = HSL[bcol * HROW + kk * 4 + quad];
            acc = MFMA(ah, bh, acc);
            acc = MFMA(ah, bl, acc);
            acc = MFMA(al, bh, acc);
          }
        }
        #pragma unroll
        for (int r = 0; r < 4; ++r)
          gx[(g * 16 + quad * 4 + r) * 32 + bcol] = acc[r];
        __syncthreads();
        {
          float gi = gx[(0 * 16 + ue) * 32 + be] + wxi + bA0;
          float gf = gx[(1 * 16 + ue) * 32 + be] + wxf + bA1;
          float gg = gx[(2 * 16 + ue) * 32 + be] + wxg + bA2;
          float go = gx[(3 * 16 + ue) * 32 + be] + wxo + bA3;
          float cc = sigmoidf_(gf) * c0r + sigmoidf_(gi) * tanhf(gg);
          float hh2 = sigmoidf_(go) * tanhf(cc);
          c0r = cc;
          unsigned h_, l_;
          bf16split(hh2, h_, l_);
          const int wpar = s & 1;
          coh_store_u16(h0h + wpar * 32768 + be * 1024 + j2e, h_);
          coh_store_u16(h0l + wpar * 32768 + be * 1024 + j2e, l_);
        }
      }
    } else if (blk < C0) {
      // ---------------- B: layer1 cell, s = t-1 -------------------------
      const int s = t - 1;
      if (s >= 0 && s < kS) {
        const int kq = w >> 2, mt = (w >> 1) & 1, nt = w & 1;
        const int rowB = mt * 16 + m;
        const int gB = rowB >> 3, uB = rowB & 7;
        const int growB = gB * 1024 + (blk - B0) * 8 + uB;
        const int bcol = nt * 16 + m;
        const short8* axh = wp1xh + quad * 4096 + growB;
        const short8* axl = wp1xl + quad * 4096 + growB;
        const short8* ahh = wp1hh + quad * 4096 + growB;
        const short8* ahl = wp1hl + quad * 4096 + growB;
        const unsigned short* p0h = h0h + (s & 1) * 32768 + bb * 1024 + kg * 8;
        const unsigned short* p0l = h0l + (s & 1) * 32768 + bb * 1024 + kg * 8;
        const unsigned short* p1h = h1h + ((s + 1) & 1) * 32768 + bb * 1024 + kg * 8;
        const unsigned short* p1l = h1l + ((s + 1) & 1) * 32768 + bb * 1024 + kg * 8;
        // queue: [h0(16), h1(16)] -> vmcnt(16) retires exactly h0
        float4 t0,t1,t2,t3,t4,t5,t6,t7, u0,u1,u2,u3,u4,u5,u6,u7;
        float4 ra0,ra1,ra2,ra3,ra4,ra5,ra6,ra7, rb0,rb1,rb2,rb3,rb4,rb5,rb6,rb7;
        ld8_coh(p0h, t0,t1,t2,t3,t4,t5,t6,t7);
        ld8_coh(p0l, u0,u1,u2,u3,u4,u5,u6,u7);
        ld8_coh(p1h, ra0,ra1,ra2,ra3,ra4,ra5,ra6,ra7);
        ld8_coh(p1l, rb0,rb1,rb2,rb3,rb4,rb5,rb6,rb7);
        VM_WAIT(16);
        HWRITE8(HSH, bb, kg, t0,t1,t2,t3,t4,t5,t6,t7);
        HWRITE8(HSL, bb, kg, u0,u1,u2,u3,u4,u5,u6,u7);
        lds_barrier();                       // h1 prefetch stays in flight
        f32x4 acc = {0.f, 0.f, 0.f, 0.f};
        // phase 1: Wx1 x h0
        #pragma unroll
        for (int k2 = 0; k2 < 16; ++k2) {
          const int kk = kq * 16 + k2;
          short8 ah = axh[kk * 16384];
          short8 al = axl[kk * 16384];
          short8 bh = HSH[bcol * HROW + kk * 4 + quad];
          short8 bl = HSL[bcol * HROW + kk * 4 + quad];
          acc = MFMA(ah, bh, acc);
          acc = MFMA(ah, bl, acc);
          acc = MFMA(al, bh, acc);
        }
        lds_barrier();                       // all waves done reading h0
        VM_WAIT(0);                          // h1 landed during phase 1
        HWRITE8(HSH, bb, kg, ra0,ra1,ra2,ra3,ra4,ra5,ra6,ra7);
        HWRITE8(HSL, bb, kg, rb0,rb1,rb2,rb3,rb4,rb5,rb6,rb7);
        lds_barrier();
        // phase 2: Wh1 x h1
        #pragma unroll
        for (int k2 = 0; k2 < 16; ++k2) {
          const int kk = kq * 16 + k2;
          short8 ah = ahh[kk * 16384];
          short8 al = ahl[kk * 16384];
          short8 bh = HSH[bcol * HROW + kk * 4 + quad];
          short8 bl = HSL[bcol * HROW + kk * 4 + quad];
          acc = MFMA(ah, bh, acc);
          acc = MFMA(ah, bl, acc);
          acc = MFMA(al, bh, acc);
        }
        #pragma unroll
        for (int r = 0; r < 4; ++r)
          gx[(kq * 32 + mt * 16 + quad * 4 + r) * 32 + bcol] = acc[r];
        __syncthreads();
        if (tid < 256) {
          const int u = tid >> 5, b = tid & 31;
          const int j2 = (blk - B0) * 8 + u;
          float gt0 = gx[(0 * 8 + u) * 32 + b] + gx[(32 + 0 * 8 + u) * 32 + b] + bB0;
          float gt1 = gx[(1 * 8 + u) * 32 + b] + gx[(32 + 1 * 8 + u) * 32 + b] + bB1;
          float gt2 = gx[(2 * 8 + u) * 32 + b] + gx[(32 + 2 * 8 + u) * 32 + b] + bB2;
          float gt3 = gx[(3 * 8 + u) * 32 + b] + gx[(32 + 3 * 8 + u) * 32 + b] + bB3;
          float cc = sigmoidf_(gt1) * c1r + sigmoidf_(gt0) * tanhf(gt2);
          float hh2 = sigmoidf_(gt3) * tanhf(cc);
          c1r = cc;
          unsigned h_, l_;
          bf16split(hh2, h_, l_);
          const int wpar = s & 1;
          coh_store_u16(h1h + wpar * 32768 + b * 1024 + j2, h_);
          coh_store_u16(h1l + wpar * 32768 + b * 1024 + j2, l_);
        }
      }
    } else {
      // ---------------- C: vocab projection, s = t-2 --------------------
      const int s = t - 2;
      if (s >= 0 && s < kS) {
        const int kq = w >> 1, nt = w & 1;
        const int growC = (blk - C0) * 16 + m;
        const int bcol = nt * 16 + m;
        const short8* aph = wyh + quad * 256 + growC;
        const short8* apl = wyl + quad * 256 + growC;
        const int rpar = s & 1;
        const unsigned short* p1h = h1h + rpar * 32768 + bb * 1024 + kg * 8;
        const unsigned short* p1l = h1l + rpar * 32768 + bb * 1024 + kg * 8;
        float4 t0,t1,t2,t3,t4,t5,t6,t7, u0,u1,u2,u3,u4,u5,u6,u7;
        ld8_coh(p1h, t0,t1,t2,t3,t4,t5,t6,t7);
        ld8_coh(p1l, u0,u1,u2,u3,u4,u5,u6,u7);
        VM_WAIT(0);
        HWRITE8(HSH, bb, kg, t0,t1,t2,t3,t4,t5,t6,t7);
        HWRITE8(HSL, bb, kg, u0,u1,u2,u3,u4,u5,u6,u7);
        __syncthreads();
        f32x4 acc = {0.f, 0.f, 0.f, 0.f};
        #pragma unroll
        for (int k2 = 0; k2 < 8; ++k2) {
          const int kk = kq * 8 + k2;
          short8 ah = aph[kk * 1024];
          short8 al = apl[kk * 1024];
          short8 bh = HSH[bcol * HROW + kk * 4 + quad];
          short8 bl = HSL[bcol * HROW + kk * 4 + quad];
          acc = MFMA(ah, bh, acc);
          acc = MFMA(ah, bl, acc);
          acc = MFMA(al, bh, acc);
        }
        #pragma unroll
        for (int r = 0; r < 4; ++r)
          gx[(kq * 16 + quad * 4 + r) * 32 + bcol] = acc[r];
        __syncthreads();
        {
          const int b = tid >> 4, vl = tid & 15;
          const int vg = (blk - C0) * 16 + vl;
          float sum = gx[(0 * 16 + vl) * 32 + b] + gx[(1 * 16 + vl) * 32 + b] +
                      gx[(2 * 16 + vl) * 32 + b] + gx[(3 * 16 + vl) * 32 + b];
          out[(s * kB + b) * kV + vg] = sum + byr;
        }
      }
    }

    // ---------------- flag barrier (contention-free, from R4) ------------
    if (t < kS + 1) {
      __syncthreads();                         // drains vmcnt per wave
      const unsigned target = (unsigned)(t + 1);
      if (tid == 0) coh_store_u32(arrive + blk * 16, target);
      if (blk == ROOT) {
        if (tid < 64) {
          const unsigned* q0 = arrive + tid * 16;
          const unsigned* q1 = arrive + (64 + tid) * 16;
          const unsigned* q2 = arrive + (128 + tid) * 16;
          const int i3 = (192 + tid < NBLK) ? (192 + tid) : 0;
          const unsigned* q3 = arrive + i3 * 16;
          int guard = 0;
          for (;;) {
            unsigned a, b, c, d;
            asm volatile(
                "global_load_dword %0, %4, off sc0 sc1\n\t"
                "global_load_dword %1, %5, off sc0 sc1\n\t"
                "global_load_dword %2, %6, off sc0 sc1\n\t"
                "global_load_dword %3, %7, off sc0 sc1\n\t"
                "s_waitcnt vmcnt(0)"
                : "=&v"(a), "=&v"(b), "=&v"(c), "=&v"(d)
                : "v"(q0), "v"(q1), "v"(q2), "v"(q3) : "memory");
            bool ok = (a >= target) && (b >= target) && (c >= target) && (d >= target);
            if (__all(ok)) break;
            if (++guard > (1 << 17)) break;    // anti-hang valve
          }
          if (tid == 0) coh_store_u32(gen, target);
        }
      } else {
        if (tid == 0) {
          int guard = 0;
          while (coh_load_u32(gen) < target) {
            __builtin_amdgcn_s_sleep(1);
            if (++guard > (1 << 17)) break;    // anti-hang valve
          }
        }
      }
      __syncthreads();
    }
  }
}

// -------------------------- host launcher ----------------------------------

extern "C" void kernel_launch(void* const* d_in, const int* in_sizes, int n_in,
                              void* d_out, int out_size, void* d_ws, size_t ws_size,
                              hipStream_t stream) {
  const int*   x   = (const int*)d_in[0];
  const float* Wx0 = (const float*)d_in[1];
  const float* Wh0 = (const float*)d_in[2];
  const float* b0v = (const float*)d_in[3];
  const float* Wx1 = (const float*)d_in[4];
  const float* Wh1 = (const float*)d_in[5];
  const float* b1v = (const float*)d_in[6];
  const float* Why = (const float*)d_in[7];
  const float* byv = (const float*)d_in[8];
  unsigned short* wss = (unsigned short*)d_ws;
  float* outp = (float*)d_out;

  hipLaunchKernelGGL(pack_w, dim3(2048), dim3(256), 0, stream,
                     Wh0, wss + WP0H, wss + WP0L, G4H);
  hipLaunchKernelGGL(pack_w, dim3(2048), dim3(256), 0, stream,
                     Wx1, wss + WP1XH, wss + WP1XL, G4H);
  hipLaunchKernelGGL(pack_w, dim3(2048), dim3(256), 0, stream,
                     Wh1, wss + WP1HH, wss + WP1HL, G4H);
  hipLaunchKernelGGL(pack_w, dim3(128), dim3(256), 0, stream,
                     Why, wss + WYH, wss + WYL, kV);
  // zero h arrays (262144 shorts = 131072 u32) + flags/gen (4097 u32)
  hipLaunchKernelGGL(zero_state, dim3(529), dim3(256), 0, stream,
                     (unsigned*)(wss + HOFF), 131072 + 4100);

  hipLaunchKernelGGL(lstm_persist, dim3(NBLK), dim3(NT), 0, stream,
                     x, Wx0, b0v, b1v, byv, wss, outp);
}

// Round 6
// 9530.518 us; speedup vs baseline: 1.3574x; 1.3574x over previous
//
#include <hip/hip_runtime.h>
#include <math.h>

// ---------------------------------------------------------------------------
// Persistent 2-layer LSTM via MFMA split-bf16 (hi+lo, 3-term) fp32 emulation.
// R12: TLP latency hiding. R6's proven per-block schedule kept verbatim
// (stage 256-k quarter -> vmcnt(0) -> sync -> compiler-scheduled weight
// loads + MFMA -> sync), but blocks halved to 256 thr and grid doubled to
// 400 so ~2 blocks co-reside per CU: one block's compute hides the other's
// stage/weight stalls (R6 counters: all pipes ~93% idle, 1 blk/CU lockstep).
// A(128)=layer0 s=t, 8 cols/blk (2 gates packed per 16-row fragment) |
// B(256)=layer1 s=t-1, 4 cols x 4 gates/blk | C(16)=proj s=t-2, 16 vg/blk.
// Per-CU MFMA/VALU work unchanged vs R6. Flag barrier resized to 400.
// ---------------------------------------------------------------------------

typedef __attribute__((ext_vector_type(8))) short short8;
typedef __attribute__((ext_vector_type(4))) float f32x4;

constexpr int kV = 256, kH = 1024, kB = 32, kS = 512, G4H = 4096;
constexpr int NT = 256, NBLK = 400;
constexpr int NA = 128, B0 = 128, C0 = 384, ROOT = NBLK - 1;

// ws layout in SHORT units
constexpr long SZW = 4194304L;            // shorts per packed 1024x4096 matrix
constexpr long SZY = 262144L;             // shorts per packed Why array
constexpr long WP0H = 0,        WP0L = SZW;
constexpr long WP1XH = 2*SZW,   WP1XL = 3*SZW;
constexpr long WP1HH = 4*SZW,   WP1HL = 5*SZW;
constexpr long WYH  = 6*SZW,    WYL  = 6*SZW + SZY;
constexpr long HOFF = 6*SZW + 2*SZY;      // h arrays: h0h[2][32K],h0l,h1h,h1l

#define MFMA(a,b,c) __builtin_amdgcn_mfma_f32_16x16x32_bf16(a, b, c, 0, 0, 0)

__device__ __forceinline__ float sigmoidf_(float v) { return 1.f / (1.f + expf(-v)); }

__device__ __forceinline__ void bf16split(float w, unsigned& hi, unsigned& lo) {
  unsigned u = __float_as_uint(w);
  unsigned r = (u + 0x7fffu + ((u >> 16) & 1u)) >> 16;
  float res = w - __uint_as_float(r << 16);
  unsigned u2 = __float_as_uint(res);
  unsigned r2 = (u2 + 0x7fffu + ((u2 >> 16) & 1u)) >> 16;
  hi = r; lo = r2;
}

// ---------------- coherent (cache-bypass) helpers --------------------------

__device__ __forceinline__ void coh_store_u32(unsigned* p, unsigned v) {
  asm volatile("global_store_dword %0, %1, off sc0 sc1" :: "v"(p), "v"(v) : "memory");
}
__device__ __forceinline__ void coh_store_u16(unsigned short* p, unsigned v) {
  asm volatile("global_store_short %0, %1, off sc0 sc1" :: "v"(p), "v"(v) : "memory");
}
__device__ __forceinline__ unsigned coh_load_u32(const unsigned* p) {
  unsigned v;
  asm volatile("global_load_dword %0, %1, off sc0 sc1\n\ts_waitcnt vmcnt(0)"
               : "=v"(v) : "v"(p) : "memory");
  return v;
}

// stage one 256-k quarter of h (hi+lo) into LDS; 256 threads, 8 loads each.
__device__ __forceinline__ void stage_q(short8* HH, short8* HL,
                                        const unsigned short* gH,
                                        const unsigned short* gL,
                                        int qtr, int tid) {
  const int r0 = tid >> 5, kg = tid & 31;            // r0 0..7
  const unsigned short* ph = gH + r0 * 1024 + qtr * 256 + kg * 8;
  const unsigned short* pl = gL + r0 * 1024 + qtr * 256 + kg * 8;
  float4 a0, a1, a2, a3, c0, c1, c2, c3;
  asm volatile(
      "global_load_dwordx4 %0, %8, off sc0 sc1\n\t"
      "global_load_dwordx4 %1, %9, off sc0 sc1\n\t"
      "global_load_dwordx4 %2, %10, off sc0 sc1\n\t"
      "global_load_dwordx4 %3, %11, off sc0 sc1\n\t"
      "global_load_dwordx4 %4, %12, off sc0 sc1\n\t"
      "global_load_dwordx4 %5, %13, off sc0 sc1\n\t"
      "global_load_dwordx4 %6, %14, off sc0 sc1\n\t"
      "global_load_dwordx4 %7, %15, off sc0 sc1\n\t"
      "s_waitcnt vmcnt(0)"
      : "=&v"(a0), "=&v"(a1), "=&v"(a2), "=&v"(a3),
        "=&v"(c0), "=&v"(c1), "=&v"(c2), "=&v"(c3)
      : "v"(ph), "v"(ph + 8192), "v"(ph + 16384), "v"(ph + 24576),
        "v"(pl), "v"(pl + 8192), "v"(pl + 16384), "v"(pl + 24576)
      : "memory");
  HH[(r0     ) * 33 + kg] = __builtin_bit_cast(short8, a0);
  HH[(r0 +  8) * 33 + kg] = __builtin_bit_cast(short8, a1);
  HH[(r0 + 16) * 33 + kg] = __builtin_bit_cast(short8, a2);
  HH[(r0 + 24) * 33 + kg] = __builtin_bit_cast(short8, a3);
  HL[(r0     ) * 33 + kg] = __builtin_bit_cast(short8, c0);
  HL[(r0 +  8) * 33 + kg] = __builtin_bit_cast(short8, c1);
  HL[(r0 + 16) * 33 + kg] = __builtin_bit_cast(short8, c2);
  HL[(r0 + 24) * 33 + kg] = __builtin_bit_cast(short8, c3);
}

// -------------------------- prep kernels -----------------------------------

__global__ void pack_w(const float* __restrict__ in, unsigned short* __restrict__ hi,
                       unsigned short* __restrict__ lo, int ncols) {
  int id = blockIdx.x * 256 + threadIdx.x;
  int slab = id / ncols, row = id % ncols;   // slab < 128
  int k0 = (slab >> 2) * 32 + (slab & 3) * 8;
  long ob = ((long)slab * ncols + row) * 8;
  #pragma unroll
  for (int e = 0; e < 8; ++e) {
    float w = in[(long)(k0 + e) * ncols + row];
    unsigned h_, l_;
    bf16split(w, h_, l_);
    hi[ob + e] = (unsigned short)h_;
    lo[ob + e] = (unsigned short)l_;
  }
}

__global__ void zero_state(unsigned* __restrict__ p, int n) {
  int i = blockIdx.x * 256 + threadIdx.x;
  if (i < n) p[i] = 0u;
}

// -------------------------- main persistent kernel -------------------------

extern "C" __global__ void __launch_bounds__(256, 2)
lstm_persist(const int* __restrict__ x,
             const float* __restrict__ Wx0,
             const float* __restrict__ b0v,
             const float* __restrict__ b1v,
             const float* __restrict__ byv,
             unsigned short* __restrict__ wss,
             float* __restrict__ out) {
  const short8* wp0h  = (const short8*)(wss + WP0H);
  const short8* wp0l  = (const short8*)(wss + WP0L);
  const short8* wp1xh = (const short8*)(wss + WP1XH);
  const short8* wp1xl = (const short8*)(wss + WP1XL);
  const short8* wp1hh = (const short8*)(wss + WP1HH);
  const short8* wp1hl = (const short8*)(wss + WP1HL);
  const short8* wyh   = (const short8*)(wss + WYH);
  const short8* wyl   = (const short8*)(wss + WYL);
  unsigned short* h0h = wss + HOFF;            // [2][32][1024]
  unsigned short* h0l = h0h + 65536;
  unsigned short* h1h = h0h + 131072;
  unsigned short* h1l = h0h + 196608;
  unsigned* arrive = (unsigned*)(h0h + 262144);  // stride-16 flags, 400 blocks
  unsigned* gen = arrive + 6400;

  const int tid = threadIdx.x, blk = blockIdx.x;
  const int lane = tid & 63, m = lane & 15, quad = lane >> 4, w = tid >> 6;

  __shared__ short8 HSH[32 * 33];   // 16.5 KB  h hi quarter
  __shared__ short8 HSL[32 * 33];   // 16.5 KB  h lo quarter
  __shared__ float gx[2048];        // 8 KB gate/output exchange

  float c0r = 0.f, c1r = 0.f;

  // ---- loop-invariant bias loads (hoisted out of the t-loop) --------------
  float bA0 = 0.f, bA1 = 0.f, bA2 = 0.f, bA3 = 0.f;
  float bB0 = 0.f, bB1 = 0.f, bB2 = 0.f, bB3 = 0.f;
  float byr = 0.f;
  if (blk < NA) {
    const int u = tid & 7, j2e0 = blk * 8 + u;
    bA0 = b0v[j2e0];           bA1 = b0v[kH + j2e0];
    bA2 = b0v[2 * kH + j2e0];  bA3 = b0v[3 * kH + j2e0];
  } else if (blk < C0) {
    if (tid < 128) {
      const int u = tid & 3, j2b = (blk - B0) * 4 + u;
      bB0 = b1v[j2b];          bB1 = b1v[kH + j2b];
      bB2 = b1v[2 * kH + j2b]; bB3 = b1v[3 * kH + j2b];
    }
  } else {
    byr = byv[(blk - C0) * 16 + (tid & 15)];
  }

  #pragma unroll 1
  for (int t = 0; t < kS + 2; ++t) {
    if (blk < NA) {
      // ---------------- A: layer0 cell, s = t ---------------------------
      const int s = t;
      if (s < kS) {
        const int gp = w >> 1, nt = w & 1;       // 4 waves: gate-pair x nt
        const int j0A = blk * 8;
        const int bcol = nt * 16 + m;
        // fragment row m -> (gate 2gp + (m>>3), col j0A + (m&7))
        const int rowA = (2 * gp + (m >> 3)) * 1024 + j0A + (m & 7);
        const short8* aph = wp0h + quad * 4096 + rowA;
        const short8* apl = wp0l + quad * 4096 + rowA;
        const int rpar = (s + 1) & 1;
        const unsigned short* gH = h0h + rpar * 32768;
        const unsigned short* gL = h0l + rpar * 32768;
        // early epilogue token load (coalesced h-store mapping)
        const int ue = tid & 7, be = tid >> 3, j2e = j0A + ue;
        const int xs = x[be * kS + s];
        f32x4 acc = {0.f, 0.f, 0.f, 0.f};
        #pragma unroll 1
        for (int qtr = 0; qtr < 4; ++qtr) {
          stage_q(HSH, HSL, gH, gL, qtr, tid);
          __syncthreads();
          #pragma unroll
          for (int kl = 0; kl < 8; ++kl) {
            const int kk = qtr * 8 + kl;
            short8 ah = aph[kk * 16384];
            short8 al = apl[kk * 16384];
            short8 bh = HSH[bcol * 33 + kl * 4 + quad];
            short8 bl = HSL[bcol * 33 + kl * 4 + quad];
            acc = MFMA(ah, bh, acc);
            acc = MFMA(ah, bl, acc);
            acc = MFMA(al, bh, acc);
          }
          __syncthreads();
        }
        #pragma unroll
        for (int r = 0; r < 4; ++r) {
          const int rr = quad * 4 + r;
          gx[((2 * gp + (rr >> 3)) * 8 + (rr & 7)) * 32 + bcol] = acc[r];
        }
        __syncthreads();
        {
          const float* wxp = Wx0 + (long)xs * G4H + j2e;
          float gi = gx[(0 * 8 + ue) * 32 + be] + wxp[0]      + bA0;
          float gf = gx[(1 * 8 + ue) * 32 + be] + wxp[kH]     + bA1;
          float gg = gx[(2 * 8 + ue) * 32 + be] + wxp[2 * kH] + bA2;
          float go = gx[(3 * 8 + ue) * 32 + be] + wxp[3 * kH] + bA3;
          float cc = sigmoidf_(gf) * c0r + sigmoidf_(gi) * tanhf(gg);
          float hh = sigmoidf_(go) * tanhf(cc);
          c0r = cc;
          unsigned h_, l_;
          bf16split(hh, h_, l_);
          const int wpar = s & 1;
          coh_store_u16(h0h + wpar * 32768 + be * 1024 + j2e, h_);
          coh_store_u16(h0l + wpar * 32768 + be * 1024 + j2e, l_);
        }
      }
    } else if (blk < C0) {
      // ---------------- B: layer1 cell, s = t-1 -------------------------
      const int s = t - 1;
      if (s >= 0 && s < kS) {
        const int kq = w >> 1, nt = w & 1;       // 4 waves: k-half x nt
        // fragment row m -> (gate m>>2, col (blk-B0)*4 + (m&3))
        const int rowB = (m >> 2) * 1024 + (blk - B0) * 4 + (m & 3);
        const int bcol = nt * 16 + m;
        f32x4 acc = {0.f, 0.f, 0.f, 0.f};
        #pragma unroll 1
        for (int ph = 0; ph < 8; ++ph) {
          const int hf = ph >> 2, qtr = ph & 3;
          const int rpar = hf ? ((s + 1) & 1) : (s & 1);
          const unsigned short* gH = (hf ? h1h : h0h) + rpar * 32768;
          const unsigned short* gL = (hf ? h1l : h0l) + rpar * 32768;
          const short8* aph = (hf ? wp1hh : wp1xh) + quad * 4096 + rowB;
          const short8* apl = (hf ? wp1hl : wp1xl) + quad * 4096 + rowB;
          stage_q(HSH, HSL, gH, gL, qtr, tid);
          __syncthreads();
          #pragma unroll
          for (int k2 = 0; k2 < 4; ++k2) {
            const int kl = kq * 4 + k2;
            const int kk = qtr * 8 + kl;
            short8 ah = aph[kk * 16384];
            short8 al = apl[kk * 16384];
            short8 bh = HSH[bcol * 33 + kl * 4 + quad];
            short8 bl = HSL[bcol * 33 + kl * 4 + quad];
            acc = MFMA(ah, bh, acc);
            acc = MFMA(ah, bl, acc);
            acc = MFMA(al, bh, acc);
          }
          __syncthreads();
        }
        #pragma unroll
        for (int r = 0; r < 4; ++r)
          gx[(kq * 16 + quad * 4 + r) * 32 + bcol] = acc[r];
        __syncthreads();
        if (tid < 128) {
          const int u = tid & 3, b = tid >> 2;   // coalesced h-store mapping
          const int j2 = (blk - B0) * 4 + u;
          float gt0 = gx[(0 * 4 + u) * 32 + b] + gx[(16 + 0 * 4 + u) * 32 + b] + bB0;
          float gt1 = gx[(1 * 4 + u) * 32 + b] + gx[(16 + 1 * 4 + u) * 32 + b] + bB1;
          float gt2 = gx[(2 * 4 + u) * 32 + b] + gx[(16 + 2 * 4 + u) * 32 + b] + bB2;
          float gt3 = gx[(3 * 4 + u) * 32 + b] + gx[(16 + 3 * 4 + u) * 32 + b] + bB3;
          float cc = sigmoidf_(gt1) * c1r + sigmoidf_(gt0) * tanhf(gt2);
          float hh = sigmoidf_(gt3) * tanhf(cc);
          c1r = cc;
          unsigned h_, l_;
          bf16split(hh, h_, l_);
          const int wpar = s & 1;
          coh_store_u16(h1h + wpar * 32768 + b * 1024 + j2, h_);
          coh_store_u16(h1l + wpar * 32768 + b * 1024 + j2, l_);
        }
      }
    } else {
      // ---------------- C: vocab projection, s = t-2 --------------------
      const int s = t - 2;
      if (s >= 0 && s < kS) {
        const int kq = w >> 1, nt = w & 1;       // 4 waves: k-half x nt
        const int growC = (blk - C0) * 16 + m;
        const int bcol = nt * 16 + m;
        const short8* aph = wyh + quad * 256 + growC;
        const short8* apl = wyl + quad * 256 + growC;
        const int rpar = s & 1;
        const unsigned short* gH = h1h + rpar * 32768;
        const unsigned short* gL = h1l + rpar * 32768;
        f32x4 acc = {0.f, 0.f, 0.f, 0.f};
        #pragma unroll 1
        for (int qtr = 0; qtr < 4; ++qtr) {
          stage_q(HSH, HSL, gH, gL, qtr, tid);
          __syncthreads();
          #pragma unroll
          for (int k2 = 0; k2 < 4; ++k2) {
            const int kl = kq * 4 + k2;
            const int kk = qtr * 8 + kl;
            short8 ah = aph[kk * 1024];
            short8 al = apl[kk * 1024];
            short8 bh = HSH[bcol * 33 + kl * 4 + quad];
            short8 bl = HSL[bcol * 33 + kl * 4 + quad];
            acc = MFMA(ah, bh, acc);
            acc = MFMA(ah, bl, acc);
            acc = MFMA(al, bh, acc);
          }
          __syncthreads();
        }
        #pragma unroll
        for (int r = 0; r < 4; ++r)
          gx[(kq * 16 + quad * 4 + r) * 32 + bcol] = acc[r];
        __syncthreads();
        {
          const int vl = tid & 15, b2 = tid >> 4;   // b2 0..15, two batches
          const int vg = (blk - C0) * 16 + vl;
          float s0 = gx[vl * 32 + b2]      + gx[(16 + vl) * 32 + b2]      + byr;
          float s1 = gx[vl * 32 + b2 + 16] + gx[(16 + vl) * 32 + b2 + 16] + byr;
          out[(s * kB + b2) * kV + vg] = s0;
          out[(s * kB + b2 + 16) * kV + vg] = s1;
        }
      }
    }

    // ---------------- flag barrier (contention-free, 400 blocks) ---------
    if (t < kS + 1) {
      __syncthreads();                         // drains vmcnt per wave
      const unsigned target = (unsigned)(t + 1);
      if (tid == 0) coh_store_u32(arrive + blk * 16, target);
      if (blk == ROOT) {
        if (tid < 64) {
          int i0 = tid;
          int i1 = tid + 64, i2 = tid + 128, i3 = tid + 192;
          int i4 = tid + 256, i5 = tid + 320, i6 = tid + 384;
          if (i6 >= NBLK) i6 = 0;              // 384..447 clamp
          const unsigned* q0 = arrive + i0 * 16;
          const unsigned* q1 = arrive + i1 * 16;
          const unsigned* q2 = arrive + i2 * 16;
          const unsigned* q3 = arrive + i3 * 16;
          const unsigned* q4 = arrive + i4 * 16;
          const unsigned* q5 = arrive + i5 * 16;
          const unsigned* q6 = arrive + i6 * 16;
          int guard = 0;
          for (;;) {
            unsigned a, b, c, d, e, f, g;
            asm volatile(
                "global_load_dword %0, %7, off sc0 sc1\n\t"
                "global_load_dword %1, %8, off sc0 sc1\n\t"
                "global_load_dword %2, %9, off sc0 sc1\n\t"
                "global_load_dword %3, %10, off sc0 sc1\n\t"
                "global_load_dword %4, %11, off sc0 sc1\n\t"
                "global_load_dword %5, %12, off sc0 sc1\n\t"
                "global_load_dword %6, %13, off sc0 sc1\n\t"
                "s_waitcnt vmcnt(0)"
                : "=&v"(a), "=&v"(b), "=&v"(c), "=&v"(d),
                  "=&v"(e), "=&v"(f), "=&v"(g)
                : "v"(q0), "v"(q1), "v"(q2), "v"(q3),
                  "v"(q4), "v"(q5), "v"(q6) : "memory");
            bool ok = (a >= target) && (b >= target) && (c >= target) &&
                      (d >= target) && (e >= target) && (f >= target) &&
                      (g >= target);
            if (__all(ok)) break;
            if (++guard > (1 << 17)) break;    // anti-hang valve
          }
          if (tid == 0) coh_store_u32(gen, target);
        }
      } else {
        if (tid == 0) {
          int guard = 0;
          while (coh_load_u32(gen) < target) {
            __builtin_amdgcn_s_sleep(1);
            if (++guard > (1 << 17)) break;    // anti-hang valve
          }
        }
      }
      __syncthreads();
    }
  }
}

// -------------------------- host launcher ----------------------------------

extern "C" void kernel_launch(void* const* d_in, const int* in_sizes, int n_in,
                              void* d_out, int out_size, void* d_ws, size_t ws_size,
                              hipStream_t stream) {
  const int*   x   = (const int*)d_in[0];
  const float* Wx0 = (const float*)d_in[1];
  const float* Wh0 = (const float*)d_in[2];
  const float* b0v = (const float*)d_in[3];
  const float* Wx1 = (const float*)d_in[4];
  const float* Wh1 = (const float*)d_in[5];
  const float* b1v = (const float*)d_in[6];
  const float* Why = (const float*)d_in[7];
  const float* byv = (const float*)d_in[8];
  unsigned short* wss = (unsigned short*)d_ws;
  float* outp = (float*)d_out;

  hipLaunchKernelGGL(pack_w, dim3(2048), dim3(256), 0, stream,
                     Wh0, wss + WP0H, wss + WP0L, G4H);
  hipLaunchKernelGGL(pack_w, dim3(2048), dim3(256), 0, stream,
                     Wx1, wss + WP1XH, wss + WP1XL, G4H);
  hipLaunchKernelGGL(pack_w, dim3(2048), dim3(256), 0, stream,
                     Wh1, wss + WP1HH, wss + WP1HL, G4H);
  hipLaunchKernelGGL(pack_w, dim3(128), dim3(256), 0, stream,
                     Why, wss + WYH, wss + WYL, kV);
  // zero h arrays (262144 shorts = 131072 u32) + flags/gen (6401 u32)
  hipLaunchKernelGGL(zero_state, dim3(538), dim3(256), 0, stream,
                     (unsigned*)(wss + HOFF), 131072 + 6500);

  hipLaunchKernelGGL(lstm_persist, dim3(NBLK), dim3(NT), 0, stream,
                     x, Wx0, b0v, b1v, byv, wss, outp);
}

// Round 7
// 4123.940 us; speedup vs baseline: 3.1371x; 2.3110x over previous
//
#include <hip/hip_runtime.h>
#include <math.h>

// ---------------------------------------------------------------------------
// Persistent 2-layer LSTM via MFMA split-bf16 (hi+lo, 3-term) fp32 emulation.
// 208 blocks x 512 thr (1/CU). Pipeline: A(64)=layer0 s=t | B(128)=layer1
// s=t-1 | C(16)=proj s=t-2. R4 flag barrier.
// R13: PERSISTENT-REGISTER WEIGHTS. Each wave owns a disjoint (row,k-parity)
// weight slice (128 VGPR) preloaded ONCE via asm; t-loop has ZERO weight
// loads. Waves compute both batch halves (nt) from their slice; partials
// reduced through 16KB gx. h-staging is the only in-loop VMEM -> clean
// double-buffered async quarters, counted vmcnt(4), one raw barrier/phase.
// Three separate t-loops (per role) isolate register pressure.
// ---------------------------------------------------------------------------

typedef __attribute__((ext_vector_type(8))) short short8;
typedef __attribute__((ext_vector_type(4))) float f32x4;

constexpr int kV = 256, kH = 1024, kB = 32, kS = 512, G4H = 4096;
constexpr int NT = 512, NBLK = 208;
constexpr int NA = 64, B0 = 64, C0 = 192, ROOT = NBLK - 1;

// ws layout in SHORT units
constexpr long SZW = 4194304L;            // shorts per packed 1024x4096 matrix
constexpr long SZY = 262144L;             // shorts per packed Why array
constexpr long WP0H = 0,        WP0L = SZW;
constexpr long WP1XH = 2*SZW,   WP1XL = 3*SZW;
constexpr long WP1HH = 4*SZW,   WP1HL = 5*SZW;
constexpr long WYH  = 6*SZW,    WYL  = 6*SZW + SZY;
constexpr long HOFF = 6*SZW + 2*SZY;      // h arrays: h0h[2][32K],h0l,h1h,h1l

#define MFMA(a,b,c) __builtin_amdgcn_mfma_f32_16x16x32_bf16(a, b, c, 0, 0, 0)

#define VM_WAIT(n) do { \
    asm volatile("s_waitcnt vmcnt(" #n ")" ::: "memory"); \
    __builtin_amdgcn_sched_barrier(0); \
  } while (0)

// asm weight load (prevents compiler rematerialization from memory)
#define WLOAD(dst, p) \
  asm volatile("global_load_dwordx4 %0, %1, off" : "=v"(dst) : "v"(p) : "memory")

__device__ __forceinline__ float sigmoidf_(float v) { return 1.f / (1.f + expf(-v)); }

__device__ __forceinline__ void bf16split(float w, unsigned& hi, unsigned& lo) {
  unsigned u = __float_as_uint(w);
  unsigned r = (u + 0x7fffu + ((u >> 16) & 1u)) >> 16;
  float res = w - __uint_as_float(r << 16);
  unsigned u2 = __float_as_uint(res);
  unsigned r2 = (u2 + 0x7fffu + ((u2 >> 16) & 1u)) >> 16;
  hi = r; lo = r2;
}

// ---------------- coherent (cache-bypass) helpers --------------------------

__device__ __forceinline__ void coh_store_u32(unsigned* p, unsigned v) {
  asm volatile("global_store_dword %0, %1, off sc0 sc1" :: "v"(p), "v"(v) : "memory");
}
__device__ __forceinline__ void coh_store_u16(unsigned short* p, unsigned v) {
  asm volatile("global_store_short %0, %1, off sc0 sc1" :: "v"(p), "v"(v) : "memory");
}
__device__ __forceinline__ unsigned coh_load_u32(const unsigned* p) {
  unsigned v;
  asm volatile("global_load_dword %0, %1, off sc0 sc1\n\ts_waitcnt vmcnt(0)"
               : "=v"(v) : "v"(p) : "memory");
  return v;
}

// issue one 256-k quarter of h (hi+lo): 4 coherent 16B loads, NO wait.
__device__ __forceinline__ void stage_issue4(const unsigned short* pr0h,
                                             const unsigned short* pr1h,
                                             const unsigned short* pr0l,
                                             const unsigned short* pr1l,
                                             int qoff,   // qtr*256 (shorts)
                                             float4& a, float4& b,
                                             float4& c, float4& d) {
  asm volatile(
      "global_load_dwordx4 %0, %4, off sc0 sc1\n\t"
      "global_load_dwordx4 %1, %5, off sc0 sc1\n\t"
      "global_load_dwordx4 %2, %6, off sc0 sc1\n\t"
      "global_load_dwordx4 %3, %7, off sc0 sc1"
      : "=&v"(a), "=&v"(b), "=&v"(c), "=&v"(d)
      : "v"(pr0h + qoff), "v"(pr1h + qoff), "v"(pr0l + qoff), "v"(pr1l + qoff)
      : "memory");
}

__device__ __forceinline__ void stage_write4(short8* HH, short8* HL,
                                             int b0_, int kg,
                                             const float4& a, const float4& b,
                                             const float4& c, const float4& d) {
  HH[b0_ * 33 + kg]        = __builtin_bit_cast(short8, a);
  HH[(b0_ + 16) * 33 + kg] = __builtin_bit_cast(short8, b);
  HL[b0_ * 33 + kg]        = __builtin_bit_cast(short8, c);
  HL[(b0_ + 16) * 33 + kg] = __builtin_bit_cast(short8, d);
}

// barrier that does NOT drain vmcnt: LDS-drain + raw s_barrier.
__device__ __forceinline__ void lds_barrier() {
  asm volatile("s_waitcnt lgkmcnt(0)" ::: "memory");
  __builtin_amdgcn_sched_barrier(0);
  __builtin_amdgcn_s_barrier();
  __builtin_amdgcn_sched_barrier(0);
}

// ---------------- grid-wide flag barrier (R4 structure) --------------------

__device__ __forceinline__ void flag_barrier(unsigned* arrive, unsigned* gen,
                                             int blk, int tid, int t) {
  __syncthreads();                         // drains vmcnt per wave
  const unsigned target = (unsigned)(t + 1);
  if (tid == 0) coh_store_u32(arrive + blk * 16, target);
  if (blk == ROOT) {
    if (tid < 64) {
      const unsigned* q0 = arrive + tid * 16;
      const unsigned* q1 = arrive + (64 + tid) * 16;
      const unsigned* q2 = arrive + (128 + tid) * 16;
      const int i3 = (192 + tid < NBLK) ? (192 + tid) : 0;
      const unsigned* q3 = arrive + i3 * 16;
      int guard = 0;
      for (;;) {
        unsigned a, b, c, d;
        asm volatile(
            "global_load_dword %0, %4, off sc0 sc1\n\t"
            "global_load_dword %1, %5, off sc0 sc1\n\t"
            "global_load_dword %2, %6, off sc0 sc1\n\t"
            "global_load_dword %3, %7, off sc0 sc1\n\t"
            "s_waitcnt vmcnt(0)"
            : "=&v"(a), "=&v"(b), "=&v"(c), "=&v"(d)
            : "v"(q0), "v"(q1), "v"(q2), "v"(q3) : "memory");
        bool ok = (a >= target) && (b >= target) && (c >= target) && (d >= target);
        if (__all(ok)) break;
        if (++guard > (1 << 17)) break;    // anti-hang valve
      }
      if (tid == 0) coh_store_u32(gen, target);
    }
  } else {
    if (tid == 0) {
      int guard = 0;
      while (coh_load_u32(gen) < target) {
        __builtin_amdgcn_s_sleep(1);
        if (++guard > (1 << 17)) break;    // anti-hang valve
      }
    }
  }
  __syncthreads();
}

// -------------------------- prep kernels -----------------------------------

__global__ void pack_w(const float* __restrict__ in, unsigned short* __restrict__ hi,
                       unsigned short* __restrict__ lo, int ncols) {
  int id = blockIdx.x * 256 + threadIdx.x;
  int slab = id / ncols, row = id % ncols;   // slab < 128
  int k0 = (slab >> 2) * 32 + (slab & 3) * 8;
  long ob = ((long)slab * ncols + row) * 8;
  #pragma unroll
  for (int e = 0; e < 8; ++e) {
    float w = in[(long)(k0 + e) * ncols + row];
    unsigned h_, l_;
    bf16split(w, h_, l_);
    hi[ob + e] = (unsigned short)h_;
    lo[ob + e] = (unsigned short)l_;
  }
}

__global__ void zero_state(unsigned* __restrict__ p, int n) {
  int i = blockIdx.x * 256 + threadIdx.x;
  if (i < n) p[i] = 0u;
}

// -------------------------- main persistent kernel -------------------------

extern "C" __global__ void __launch_bounds__(512, 1)
lstm_persist(const int* __restrict__ x,
             const float* __restrict__ Wx0,
             const float* __restrict__ b0v,
             const float* __restrict__ b1v,
             const float* __restrict__ byv,
             unsigned short* __restrict__ wss,
             float* __restrict__ out) {
  const short8* wp0h  = (const short8*)(wss + WP0H);
  const short8* wp0l  = (const short8*)(wss + WP0L);
  const short8* wp1xh = (const short8*)(wss + WP1XH);
  const short8* wp1xl = (const short8*)(wss + WP1XL);
  const short8* wp1hh = (const short8*)(wss + WP1HH);
  const short8* wp1hl = (const short8*)(wss + WP1HL);
  const short8* wyh   = (const short8*)(wss + WYH);
  const short8* wyl   = (const short8*)(wss + WYL);
  unsigned short* h0h = wss + HOFF;            // [2][32][1024]
  unsigned short* h0l = h0h + 65536;
  unsigned short* h1h = h0h + 131072;
  unsigned short* h1l = h0h + 196608;
  unsigned* arrive = (unsigned*)(h0h + 262144);  // stride-16 flags
  unsigned* gen = arrive + 4096;

  const int tid = threadIdx.x, blk = blockIdx.x;
  const int lane = tid & 63, m = lane & 15, quad = lane >> 4, w = tid >> 6;
  const int b0_ = tid >> 5, kg = tid & 31;     // staging row / chunk
  const int kg8 = kg * 8;

  __shared__ short8 HSH[2][32 * 33];   // 2 x 16.5 KB  h hi quarter (dbuf)
  __shared__ short8 HSL[2][32 * 33];   // 2 x 16.5 KB  h lo quarter (dbuf)
  __shared__ float gx[4096];           // 16 KB partial-sum exchange

  if (blk < NA) {
    // ================= A: layer0 cell, s = t ===========================
    const int g = w >> 1, kh = w & 1, j0A = blk * 16;
    const int ue = tid >> 5, be = tid & 31, j2e = j0A + ue;
    const float bA0 = b0v[j2e],          bA1 = b0v[kH + j2e];
    const float bA2 = b0v[2 * kH + j2e], bA3 = b0v[3 * kH + j2e];
    // persistent weight slice: 16 kk (parity kh) x hi/lo = 128 VGPR
    const short8* ah_ = wp0h + quad * 4096 + (g * 1024 + j0A + m);
    const short8* al_ = wp0l + quad * 4096 + (g * 1024 + j0A + m);
    short8 wah[16], wal[16];
    #pragma unroll
    for (int i = 0; i < 16; ++i) {
      WLOAD(wah[i], &ah_[(2 * i + kh) * 16384]);
      WLOAD(wal[i], &al_[(2 * i + kh) * 16384]);
    }
    VM_WAIT(0);
    float c0r = 0.f;

    #pragma unroll 1
    for (int t = 0; t < kS + 2; ++t) {
      const int s = t;
      if (s < kS) {
        const int rpar = (s + 1) & 1;
        const unsigned short* gH = h0h + rpar * 32768;
        const unsigned short* gL = h0l + rpar * 32768;
        const unsigned short* pH0 = gH + b0_ * 1024 + kg8;
        const unsigned short* pH1 = pH0 + 16 * 1024;
        const unsigned short* pL0 = gL + b0_ * 1024 + kg8;
        const unsigned short* pL1 = pL0 + 16 * 1024;
        // xs first (compiler load + its own drain), then asm gather, stages
        const int xs = x[be * kS + s];
        const float* wxp = Wx0 + (long)xs * G4H + j2e;
        float wxi, wxf, wxg, wxo;
        asm volatile(
            "global_load_dword %0, %4, off\n\t"
            "global_load_dword %1, %5, off\n\t"
            "global_load_dword %2, %6, off\n\t"
            "global_load_dword %3, %7, off"
            : "=&v"(wxi), "=&v"(wxf), "=&v"(wxg), "=&v"(wxo)
            : "v"(wxp), "v"(wxp + kH), "v"(wxp + 2 * kH), "v"(wxp + 3 * kH)
            : "memory");
        float4 st[2][4];
        stage_issue4(pH0, pH1, pL0, pL1, 0, st[0][0], st[0][1], st[0][2], st[0][3]);
        f32x4 acc0 = {0.f, 0.f, 0.f, 0.f}, acc1 = {0.f, 0.f, 0.f, 0.f};
        #pragma unroll
        for (int ph = 0; ph < 4; ++ph) {
          if (ph < 3)
            stage_issue4(pH0, pH1, pL0, pL1, (ph + 1) * 256,
                         st[(ph + 1) & 1][0], st[(ph + 1) & 1][1],
                         st[(ph + 1) & 1][2], st[(ph + 1) & 1][3]);
          if (ph < 3) { VM_WAIT(4); } else { VM_WAIT(0); }
          stage_write4(&HSH[ph & 1][0], &HSL[ph & 1][0], b0_, kg,
                       st[ph & 1][0], st[ph & 1][1], st[ph & 1][2], st[ph & 1][3]);
          lds_barrier();
          #pragma unroll
          for (int i2 = 0; i2 < 4; ++i2) {
            const int kl = 2 * i2 + kh;          // runtime kh, fine
            const int widx = ph * 4 + i2;        // compile-time
            short8 bh0 = HSH[ph & 1][m * 33 + kl * 4 + quad];
            short8 bl0 = HSL[ph & 1][m * 33 + kl * 4 + quad];
            short8 bh1 = HSH[ph & 1][(16 + m) * 33 + kl * 4 + quad];
            short8 bl1 = HSL[ph & 1][(16 + m) * 33 + kl * 4 + quad];
            acc0 = MFMA(wah[widx], bh0, acc0);
            acc0 = MFMA(wah[widx], bl0, acc0);
            acc0 = MFMA(wal[widx], bh0, acc0);
            acc1 = MFMA(wah[widx], bh1, acc1);
            acc1 = MFMA(wah[widx], bl1, acc1);
            acc1 = MFMA(wal[widx], bh1, acc1);
          }
        }
        #pragma unroll
        for (int r = 0; r < 4; ++r) {
          gx[(kh * 64 + g * 16 + quad * 4 + r) * 32 + m]      = acc0[r];
          gx[(kh * 64 + g * 16 + quad * 4 + r) * 32 + 16 + m] = acc1[r];
        }
        lds_barrier();
        {
          float gi = gx[(0 + ue) * 32 + be]  + gx[(64 + 0 + ue) * 32 + be]  + wxi + bA0;
          float gf = gx[(16 + ue) * 32 + be] + gx[(64 + 16 + ue) * 32 + be] + wxf + bA1;
          float gg = gx[(32 + ue) * 32 + be] + gx[(64 + 32 + ue) * 32 + be] + wxg + bA2;
          float go = gx[(48 + ue) * 32 + be] + gx[(64 + 48 + ue) * 32 + be] + wxo + bA3;
          float cc = sigmoidf_(gf) * c0r + sigmoidf_(gi) * tanhf(gg);
          float hh = sigmoidf_(go) * tanhf(cc);
          c0r = cc;
          unsigned h_, l_;
          bf16split(hh, h_, l_);
          const int wpar = s & 1;
          coh_store_u16(h0h + wpar * 32768 + be * 1024 + j2e, h_);
          coh_store_u16(h0l + wpar * 32768 + be * 1024 + j2e, l_);
        }
      }
      if (t < kS + 1) flag_barrier(arrive, gen, blk, tid, t);
    }
  } else if (blk < C0) {
    // ================= B: layer1 cell, s = t-1 =========================
    const int hf = w >> 2, mt = (w >> 1) & 1, kq = w & 1;
    const int rowB = mt * 16 + m;
    const int growB = (rowB >> 3) * 1024 + (blk - B0) * 8 + (rowB & 7);
    const int ub = tid >> 5, bb2 = tid & 31;
    const int j2b = (blk - B0) * 8 + (ub & 7);
    const float bB0 = b1v[j2b],          bB1 = b1v[kH + j2b];
    const float bB2 = b1v[2 * kH + j2b], bB3 = b1v[3 * kH + j2b];
    // persistent slice: matrix hf, 16 kk (parity kq) x hi/lo = 128 VGPR
    const short8* bh_ = (hf ? wp1hh : wp1xh) + quad * 4096 + growB;
    const short8* bl_ = (hf ? wp1hl : wp1xl) + quad * 4096 + growB;
    short8 wbh[16], wbl[16];
    #pragma unroll
    for (int i = 0; i < 16; ++i) {
      WLOAD(wbh[i], &bh_[(2 * i + kq) * 16384]);
      WLOAD(wbl[i], &bl_[(2 * i + kq) * 16384]);
    }
    VM_WAIT(0);
    float c1r = 0.f;

    #pragma unroll 1
    for (int t = 0; t < kS + 2; ++t) {
      const int s = t - 1;
      if (s >= 0 && s < kS) {
        const unsigned short* g0h = h0h + (s & 1) * 32768;
        const unsigned short* g0l = h0l + (s & 1) * 32768;
        const unsigned short* g1h = h1h + ((s + 1) & 1) * 32768;
        const unsigned short* g1l = h1l + ((s + 1) & 1) * 32768;
        const unsigned short* pA0h = g0h + b0_ * 1024 + kg8;
        const unsigned short* pA1h = pA0h + 16 * 1024;
        const unsigned short* pA0l = g0l + b0_ * 1024 + kg8;
        const unsigned short* pA1l = pA0l + 16 * 1024;
        const unsigned short* pB0h = g1h + b0_ * 1024 + kg8;
        const unsigned short* pB1h = pB0h + 16 * 1024;
        const unsigned short* pB0l = g1l + b0_ * 1024 + kg8;
        const unsigned short* pB1l = pB0l + 16 * 1024;
        float4 st[2][4];
        stage_issue4(pA0h, pA1h, pA0l, pA1l, 0,
                     st[0][0], st[0][1], st[0][2], st[0][3]);
        f32x4 acc0 = {0.f, 0.f, 0.f, 0.f}, acc1 = {0.f, 0.f, 0.f, 0.f};
        #pragma unroll
        for (int ph = 0; ph < 8; ++ph) {
          const int half = ph >> 2, qtr = ph & 3;
          if (ph < 7) {
            const int p1 = ph + 1, q1 = p1 & 3;
            if ((p1 >> 2) == 0)
              stage_issue4(pA0h, pA1h, pA0l, pA1l, q1 * 256,
                           st[p1 & 1][0], st[p1 & 1][1], st[p1 & 1][2], st[p1 & 1][3]);
            else
              stage_issue4(pB0h, pB1h, pB0l, pB1l, q1 * 256,
                           st[p1 & 1][0], st[p1 & 1][1], st[p1 & 1][2], st[p1 & 1][3]);
          }
          if (ph < 7) { VM_WAIT(4); } else { VM_WAIT(0); }
          stage_write4(&HSH[ph & 1][0], &HSL[ph & 1][0], b0_, kg,
                       st[ph & 1][0], st[ph & 1][1], st[ph & 1][2], st[ph & 1][3]);
          lds_barrier();
          if (hf == half) {
            #pragma unroll
            for (int i2 = 0; i2 < 4; ++i2) {
              const int kl = 2 * i2 + kq;
              const int widx = qtr * 4 + i2;
              short8 bh0 = HSH[ph & 1][m * 33 + kl * 4 + quad];
              short8 bl0 = HSL[ph & 1][m * 33 + kl * 4 + quad];
              short8 bh1 = HSH[ph & 1][(16 + m) * 33 + kl * 4 + quad];
              short8 bl1 = HSL[ph & 1][(16 + m) * 33 + kl * 4 + quad];
              acc0 = MFMA(wbh[widx], bh0, acc0);
              acc0 = MFMA(wbh[widx], bl0, acc0);
              acc0 = MFMA(wbl[widx], bh0, acc0);
              acc1 = MFMA(wbh[widx], bh1, acc1);
              acc1 = MFMA(wbh[widx], bl1, acc1);
              acc1 = MFMA(wbl[widx], bh1, acc1);
            }
          }
        }
        #pragma unroll
        for (int r = 0; r < 4; ++r) {
          const int rg = hf * 2 + kq;
          gx[(rg * 32 + mt * 16 + quad * 4 + r) * 32 + m]      = acc0[r];
          gx[(rg * 32 + mt * 16 + quad * 4 + r) * 32 + 16 + m] = acc1[r];
        }
        lds_barrier();
        if (tid < 256) {
          const int u = tid >> 5, b = tid & 31;
          float gt[4];
          #pragma unroll
          for (int g2 = 0; g2 < 4; ++g2) {
            const int row = g2 * 8 + u;
            gt[g2] = gx[(row) * 32 + b] + gx[(32 + row) * 32 + b] +
                     gx[(64 + row) * 32 + b] + gx[(96 + row) * 32 + b];
          }
          float gt0 = gt[0] + bB0, gt1 = gt[1] + bB1;
          float gt2 = gt[2] + bB2, gt3 = gt[3] + bB3;
          float cc = sigmoidf_(gt1) * c1r + sigmoidf_(gt0) * tanhf(gt2);
          float hh = sigmoidf_(gt3) * tanhf(cc);
          c1r = cc;
          unsigned h_, l_;
          bf16split(hh, h_, l_);
          const int wpar = s & 1;
          const int j2 = (blk - B0) * 8 + u;
          coh_store_u16(h1h + wpar * 32768 + b * 1024 + j2, h_);
          coh_store_u16(h1l + wpar * 32768 + b * 1024 + j2, l_);
        }
        (void)ub; (void)bb2;
      }
      if (t < kS + 1) flag_barrier(arrive, gen, blk, tid, t);
    }
  } else {
    // ================= C: vocab projection, s = t-2 ====================
    const int growC = (blk - C0) * 16 + m;
    const float byr = byv[(blk - C0) * 16 + (tid & 15)];
    // persistent slice: 4 kk (kl == w) x hi/lo = 32 VGPR
    const short8* ch_ = wyh + quad * 256 + growC;
    const short8* cl_ = wyl + quad * 256 + growC;
    short8 wch[4], wcl[4];
    #pragma unroll
    for (int i = 0; i < 4; ++i) {
      WLOAD(wch[i], &ch_[(i * 8 + w) * 1024]);
      WLOAD(wcl[i], &cl_[(i * 8 + w) * 1024]);
    }
    VM_WAIT(0);

    #pragma unroll 1
    for (int t = 0; t < kS + 2; ++t) {
      const int s = t - 2;
      if (s >= 0 && s < kS) {
        const int rpar = s & 1;
        const unsigned short* gH = h1h + rpar * 32768;
        const unsigned short* gL = h1l + rpar * 32768;
        const unsigned short* pH0 = gH + b0_ * 1024 + kg8;
        const unsigned short* pH1 = pH0 + 16 * 1024;
        const unsigned short* pL0 = gL + b0_ * 1024 + kg8;
        const unsigned short* pL1 = pL0 + 16 * 1024;
        float4 st[2][4];
        stage_issue4(pH0, pH1, pL0, pL1, 0, st[0][0], st[0][1], st[0][2], st[0][3]);
        f32x4 acc0 = {0.f, 0.f, 0.f, 0.f}, acc1 = {0.f, 0.f, 0.f, 0.f};
        #pragma unroll
        for (int ph = 0; ph < 4; ++ph) {
          if (ph < 3)
            stage_issue4(pH0, pH1, pL0, pL1, (ph + 1) * 256,
                         st[(ph + 1) & 1][0], st[(ph + 1) & 1][1],
                         st[(ph + 1) & 1][2], st[(ph + 1) & 1][3]);
          if (ph < 3) { VM_WAIT(4); } else { VM_WAIT(0); }
          stage_write4(&HSH[ph & 1][0], &HSL[ph & 1][0], b0_, kg,
                       st[ph & 1][0], st[ph & 1][1], st[ph & 1][2], st[ph & 1][3]);
          lds_barrier();
          {
            const int kl = w;                  // wave-uniform
            short8 bh0 = HSH[ph & 1][m * 33 + kl * 4 + quad];
            short8 bl0 = HSL[ph & 1][m * 33 + kl * 4 + quad];
            short8 bh1 = HSH[ph & 1][(16 + m) * 33 + kl * 4 + quad];
            short8 bl1 = HSL[ph & 1][(16 + m) * 33 + kl * 4 + quad];
            acc0 = MFMA(wch[ph], bh0, acc0);
            acc0 = MFMA(wch[ph], bl0, acc0);
            acc0 = MFMA(wcl[ph], bh0, acc0);
            acc1 = MFMA(wch[ph], bh1, acc1);
            acc1 = MFMA(wch[ph], bl1, acc1);
            acc1 = MFMA(wcl[ph], bh1, acc1);
          }
        }
        #pragma unroll
        for (int r = 0; r < 4; ++r) {
          gx[(w * 16 + quad * 4 + r) * 32 + m]      = acc0[r];
          gx[(w * 16 + quad * 4 + r) * 32 + 16 + m] = acc1[r];
        }
        lds_barrier();
        {
          const int b = tid >> 4, vl = tid & 15;
          const int vg = (blk - C0) * 16 + vl;
          float sum = byr;
          #pragma unroll
          for (int rg = 0; rg < 8; ++rg) sum += gx[(rg * 16 + vl) * 32 + b];
          out[(s * kB + b) * kV + vg] = sum;
        }
      }
      if (t < kS + 1) flag_barrier(arrive, gen, blk, tid, t);
    }
  }
}

// -------------------------- host launcher ----------------------------------

extern "C" void kernel_launch(void* const* d_in, const int* in_sizes, int n_in,
                              void* d_out, int out_size, void* d_ws, size_t ws_size,
                              hipStream_t stream) {
  const int*   x   = (const int*)d_in[0];
  const float* Wx0 = (const float*)d_in[1];
  const float* Wh0 = (const float*)d_in[2];
  const float* b0v = (const float*)d_in[3];
  const float* Wx1 = (const float*)d_in[4];
  const float* Wh1 = (const float*)d_in[5];
  const float* b1v = (const float*)d_in[6];
  const float* Why = (const float*)d_in[7];
  const float* byv = (const float*)d_in[8];
  unsigned short* wss = (unsigned short*)d_ws;
  float* outp = (float*)d_out;

  hipLaunchKernelGGL(pack_w, dim3(2048), dim3(256), 0, stream,
                     Wh0, wss + WP0H, wss + WP0L, G4H);
  hipLaunchKernelGGL(pack_w, dim3(2048), dim3(256), 0, stream,
                     Wx1, wss + WP1XH, wss + WP1XL, G4H);
  hipLaunchKernelGGL(pack_w, dim3(2048), dim3(256), 0, stream,
                     Wh1, wss + WP1HH, wss + WP1HL, G4H);
  hipLaunchKernelGGL(pack_w, dim3(128), dim3(256), 0, stream,
                     Why, wss + WYH, wss + WYL, kV);
  // zero h arrays (262144 shorts = 131072 u32) + flags/gen (4097 u32)
  hipLaunchKernelGGL(zero_state, dim3(529), dim3(256), 0, stream,
                     (unsigned*)(wss + HOFF), 131072 + 4100);

  hipLaunchKernelGGL(lstm_persist, dim3(NBLK), dim3(NT), 0, stream,
                     x, Wx0, b0v, b1v, byv, wss, outp);
}